// Round 5
// baseline (226.147 us; speedup 1.0000x reference)
//
#include <hip/hip_runtime.h>
#include <hip/hip_cooperative_groups.h>

namespace cg = cooperative_groups;

// Problem constants (fixed by reference setup_inputs)
#define N_PRE 8192
#define N_CUR 16384
#define KNN   8

// Workspace layout (bytes):
//   [0,    64K) : c2p  u32[N_CUR]     nearest-pre index per cur point
//   [64K, 192K) : pre4 float4[N_PRE]  (-2px, -2py, -2pz, |p|^2)
//   [192K,448K) : cur4 float4[N_CUR]  ( cx,   cy,   cz,  |c|^2)
//
// Comparator trick: for a fixed query q, ordering by true sqdist equals
// ordering by (|cand|^2 - 2 cand.q)  -> 3 FMA per candidate.
// d can be NEGATIVE -> monotone float->u32 key map for all key compares.
//
// R5: ONE cooperative kernel (prep -> grid.sync -> A -> grid.sync -> B).
// Rationale: R0-R4 totals minus per-dispatch counter times expose ~44us of
// fixed multi-launch overhead (3 kernels); R3/R4 cross-check gives
// A(LDS)~30us, B(R4)=57.3us. Fusing removes ~2 launch gaps.
//  A-phase: measured-best structure (LDS pre-tile, Q=4 queries/wave,
//    branchless running min, packed (key<<32|idx) u64 butterfly).
//  B-phase: R4 verbatim (LDS cur-tile, P=2 pre/wave, ballot-pop with
//    DPP row_shr:1 + readlane insert — no LDS-pipe ops in events).
// Grid 512 x 512thr x 32KB LDS = 2 blocks/CU co-resident (coop cap 4/CU).

#define MAPPED_INF 0xFF800000u  // monotone key of +inf (empty-slot sentinel)

__device__ __forceinline__ unsigned key_of_bits(unsigned b) {
    return b ^ (0x80000000u | (unsigned)((int)b >> 31));
}
__device__ __forceinline__ float float_of_key(unsigned k) {
    unsigned b = k ^ (0x80000000u | ~(unsigned)((int)k >> 31));
    return __uint_as_float(b);
}

// B-phase pop: list distributed on lanes 0..7 (ascending keys).
// Event: ballot -> s_ff1 -> readlane (uniform key) -> DPP shift-up ->
// 2 cmp + 4 cndmask -> readlane new threshold. Proven R4 (57.3us, exact).
__device__ __forceinline__ void pop_top8(float d, float& t8, unsigned& ld,
                                         unsigned& li, int jbase) {
    unsigned long long m = __ballot(d < t8);
    while (m) {
        int src = __ffsll(m) - 1;
        unsigned fdb = (unsigned)__builtin_amdgcn_readlane(__float_as_int(d), src);
        unsigned kd = key_of_bits(fdb);            // uniform (SALU)
        unsigned kj = (unsigned)(jbase + src);     // uniform (SALU)
        // shift-up within 16-lane row; lane 0 receives old=0 (key 0 = -inf
        // sentinel below -> lane 0 never takes the shifted value)
        unsigned ud = (unsigned)__builtin_amdgcn_update_dpp(
            0, (int)ld, 0x111, 0xF, 0xF, false);
        unsigned uj = (unsigned)__builtin_amdgcn_update_dpp(
            0, (int)li, 0x111, 0xF, 0xF, false);
        bool hi = kd < ud;   // belongs below slot-1 -> take shifted value
        bool lo = kd < ld;   // belongs here -> take new
        ld = hi ? ud : (lo ? kd : ld);
        li = hi ? uj : (lo ? kj : li);
        unsigned k7 = (unsigned)__builtin_amdgcn_readlane((int)ld, 7);
        t8 = float_of_key(k7);
        m = (m & (m - 1)) & __ballot(d < t8);
    }
}

#define TILE 2048   // float4 elements staged in LDS (32 KB)

__global__ __launch_bounds__(512, 4) void fused_kernel(
        const float* __restrict__ pre, const float* __restrict__ cur,
        const float* __restrict__ ups,
        float4* __restrict__ pre4, float4* __restrict__ cur4,
        unsigned* __restrict__ c2p, float* __restrict__ out) {
    __shared__ float4 sbuf[TILE];
    cg::grid_group grid = cg::this_grid();

    const int tid  = threadIdx.x;
    const int lane = tid & 63;
    const int w    = tid >> 6;
    const int gi   = blockIdx.x * 512 + tid;   // 0 .. 262143

    // ---------------- phase 0: prep (pack comparator-form coords) -------
    if (gi < N_CUR) {
        float x = cur[gi], y = cur[N_CUR + gi], z = cur[2 * N_CUR + gi];
        cur4[gi] = make_float4(x, y, z, fmaf(x, x, fmaf(y, y, z * z)));
    }
    if (gi < N_PRE) {
        float x = pre[gi], y = pre[N_PRE + gi], z = pre[2 * N_PRE + gi];
        pre4[gi] = make_float4(-2.f * x, -2.f * y, -2.f * z,
                               fmaf(x, x, fmaf(y, y, z * z)));
    }
    grid.sync();

    // ---------------- phase A: cur2pre argmin ----------------------------
    // Wave owns Q=4 cur queries (regs); lanes scan pre from the LDS tile.
    // Branchless running min; strict < + ascending per-lane idx stream ->
    // lowest index on ties; cross-lane packed u64 butterfly min.
    {
        const int wv = gi >> 6;        // 0 .. 4095
        const int j0 = wv * 4;

        const float4 c0 = cur4[j0 + 0];
        const float4 c1 = cur4[j0 + 1];
        const float4 c2 = cur4[j0 + 2];
        const float4 c3 = cur4[j0 + 3];

        const float INF = __int_as_float(0x7F800000);
        float b0 = INF, b1 = INF, b2 = INF, b3 = INF;
        int   i0 = 0,  i1 = 0,  i2 = 0,  i3 = 0;

        for (int tile = 0; tile < N_PRE; tile += TILE) {
            __syncthreads();
            for (int k = tid; k < TILE; k += 512) sbuf[k] = pre4[tile + k];
            __syncthreads();

#pragma unroll 4
            for (int s = 0; s < TILE; s += 64) {
                float4 q = sbuf[s + lane];
                int idx = tile + s + lane;
                float d; bool c;
                d = fmaf(q.x, c0.x, fmaf(q.y, c0.y, fmaf(q.z, c0.z, q.w)));
                c = d < b0; b0 = c ? d : b0; i0 = c ? idx : i0;
                d = fmaf(q.x, c1.x, fmaf(q.y, c1.y, fmaf(q.z, c1.z, q.w)));
                c = d < b1; b1 = c ? d : b1; i1 = c ? idx : i1;
                d = fmaf(q.x, c2.x, fmaf(q.y, c2.y, fmaf(q.z, c2.z, q.w)));
                c = d < b2; b2 = c ? d : b2; i2 = c ? idx : i2;
                d = fmaf(q.x, c3.x, fmaf(q.y, c3.y, fmaf(q.z, c3.z, q.w)));
                c = d < b3; b3 = c ? d : b3; i3 = c ? idx : i3;
            }
        }

        unsigned long long v0 =
            (((unsigned long long)key_of_bits(__float_as_uint(b0))) << 32) | (unsigned)i0;
        unsigned long long v1 =
            (((unsigned long long)key_of_bits(__float_as_uint(b1))) << 32) | (unsigned)i1;
        unsigned long long v2 =
            (((unsigned long long)key_of_bits(__float_as_uint(b2))) << 32) | (unsigned)i2;
        unsigned long long v3 =
            (((unsigned long long)key_of_bits(__float_as_uint(b3))) << 32) | (unsigned)i3;
#pragma unroll
        for (int off = 32; off > 0; off >>= 1) {
            unsigned long long o;
            o = __shfl_xor(v0, off); v0 = (o < v0) ? o : v0;
            o = __shfl_xor(v1, off); v1 = (o < v1) ? o : v1;
            o = __shfl_xor(v2, off); v2 = (o < v2) ? o : v2;
            o = __shfl_xor(v3, off); v3 = (o < v3) ? o : v3;
        }
        unsigned r = (unsigned)v0;
        r = (lane == 1) ? (unsigned)v1 : r;
        r = (lane == 2) ? (unsigned)v2 : r;
        r = (lane == 3) ? (unsigned)v3 : r;
        if (lane < 4) c2p[j0 + lane] = r;
    }
    grid.sync();

    // ---------------- phase B: per-pre top-8 + masked mean ---------------
    // R4 structure verbatim: 8 waves x P=2 pre each; LDS cur tile; ballot-
    // gated pop events with DPP insert.
    {
        const int ia = blockIdx.x * 16 + w * 2;
        const int ib = ia + 1;

        const float4 p0 = pre4[ia];   // (-2p, |p|^2), wave-uniform
        const float4 p1 = pre4[ib];

        const float INF = __int_as_float(0x7F800000);
        unsigned ld0 = MAPPED_INF, li0 = 0, ld1 = MAPPED_INF, li1 = 0;
        float t80 = INF, t81 = INF;

        for (int tile = 0; tile < N_CUR; tile += TILE) {
            __syncthreads();
            for (int k = tid; k < TILE; k += 512) sbuf[k] = cur4[tile + k];
            __syncthreads();

#pragma unroll 4
            for (int s = 0; s < TILE; s += 64) {
                float4 c = sbuf[s + lane];
                float d0 = fmaf(p0.x, c.x, fmaf(p0.y, c.y, fmaf(p0.z, c.z, c.w)));
                float d1 = fmaf(p1.x, c.x, fmaf(p1.y, c.y, fmaf(p1.z, c.z, c.w)));
                const int jbase = tile + s;
                pop_top8(d0, t80, ld0, li0, jbase);
                pop_top8(d1, t81, ld1, li1, jbase);
            }
        }

        // finalize: lanes 0..7 hold slots 0..7 (ascending) of each list.
        // True distance recomputed in direct form; p recovered exactly (*-0.5).
        {
            float acc = 0.f;
            if (lane < 8) {
                unsigned j = li0;
                float4 cc = cur4[j];
                float px = -0.5f * p0.x, py = -0.5f * p0.y, pz = -0.5f * p0.z;
                float dx = cc.x - px, dy = cc.y - py, dz = cc.z - pz;
                float dsq = fmaf(dx, dx, fmaf(dy, dy, dz * dz));
                acc = (c2p[j] == (unsigned)ia) ? sqrtf(dsq) : 0.f;
            }
            acc += __shfl_xor(acc, 1);
            acc += __shfl_xor(acc, 2);
            acc += __shfl_xor(acc, 4);
            if (lane == 0) out[ia] = acc / ups[ia];
        }
        {
            float acc = 0.f;
            if (lane < 8) {
                unsigned j = li1;
                float4 cc = cur4[j];
                float px = -0.5f * p1.x, py = -0.5f * p1.y, pz = -0.5f * p1.z;
                float dx = cc.x - px, dy = cc.y - py, dz = cc.z - pz;
                float dsq = fmaf(dx, dx, fmaf(dy, dy, dz * dz));
                acc = (c2p[j] == (unsigned)ib) ? sqrtf(dsq) : 0.f;
            }
            acc += __shfl_xor(acc, 1);
            acc += __shfl_xor(acc, 2);
            acc += __shfl_xor(acc, 4);
            if (lane == 0) out[ib] = acc / ups[ib];
        }
    }
}

// ---------- launch ----------
extern "C" void kernel_launch(void* const* d_in, const int* in_sizes, int n_in,
                              void* d_out, int out_size, void* d_ws, size_t ws_size,
                              hipStream_t stream) {
    const float* pre = (const float*)d_in[0];   // (1,3,8192)
    const float* cur = (const float*)d_in[1];   // (1,3,16384)
    const float* ups = (const float*)d_in[2];   // (1,8192)
    float* out = (float*)d_out;                 // (1,8192)

    char* ws = (char*)d_ws;
    unsigned* c2p = (unsigned*)ws;                    //  64 KB
    float4*   pre4 = (float4*)(ws + 65536);           // 128 KB
    float4*   cur4 = (float4*)(ws + 65536 + 131072);  // 256 KB

    void* args[] = { (void*)&pre, (void*)&cur, (void*)&ups,
                     (void*)&pre4, (void*)&cur4, (void*)&c2p, (void*)&out };

    // 512 blocks x 512 thr x 32KB LDS: 2 blocks/CU, coop-resident (cap 4/CU)
    hipLaunchCooperativeKernel((const void*)fused_kernel,
                               dim3(512), dim3(512), args, 0, stream);
}

// Round 6
// 135.568 us; speedup vs baseline: 1.6681x; 1.6681x over previous
//
#include <hip/hip_runtime.h>

// Problem constants (fixed by reference setup_inputs)
#define N_PRE 8192
#define N_CUR 16384
#define KNN   8

// Workspace layout (bytes):
//   [0,    64K) : c2p  u32[N_CUR]     nearest-pre index per cur point
//   [64K, 192K) : pre4 float4[N_PRE]  (-2px, -2py, -2pz, |p|^2)
//   [192K,448K) : cur4 float4[N_CUR]  ( cx,   cy,   cz,  |c|^2)
//
// Comparator trick: for a fixed query q, ordering by true sqdist equals
// ordering by (|cand|^2 - 2 cand.q)  -> 3 FMA per candidate.
// d can be NEGATIVE -> monotone float->u32 key map for all key compares.
//
// R6 (overhead theory resolved by R5: ~63us/iter harness cost is
// launch-count-INDEPENDENT; fusion reverted. Re-solved per-kernel times:
// A(R1 LDS-tile) ~10us, B=57.3us -> all effort on B):
//  A: R1 structure verbatim (512 blocks x 1024thr, 2 cur/wave, LDS pre
//     tile, branchless min, packed (key<<32|idx) u64 butterfly). ~10us.
//  B: cur dimension SPLIT x2 to break the 16-waves/CU structural cap
//     (waves = pres/2 was fixed): block = 8 pres, waves 0-3 scan half 0,
//     waves 4-7 scan half 1 (two 16KB tiles). 1024 blocks x 8 waves =
//     32 waves/CU. Exact in-block merge: two partial top-8 lists per pre
//     (disjoint halves, (key,idx)-lex minimal) -> 16-element bitonic
//     merge on packed u64 via shfl_xor -> global top-8, same tie-break.

#define MAPPED_INF 0xFF800000u  // monotone key of +inf (empty-slot sentinel)

__device__ __forceinline__ unsigned key_of_bits(unsigned b) {
    return b ^ (0x80000000u | (unsigned)((int)b >> 31));
}
__device__ __forceinline__ float float_of_key(unsigned k) {
    unsigned b = k ^ (0x80000000u | ~(unsigned)((int)k >> 31));
    return __uint_as_float(b);
}

// ---------- prep: pack comparator-form coords ----------
__global__ __launch_bounds__(256) void prep_kernel(
        const float* __restrict__ pre, const float* __restrict__ cur,
        float4* __restrict__ pre4, float4* __restrict__ cur4) {
    int i = blockIdx.x * 256 + threadIdx.x;
    if (i < N_CUR) {
        float x = cur[i], y = cur[N_CUR + i], z = cur[2 * N_CUR + i];
        cur4[i] = make_float4(x, y, z, fmaf(x, x, fmaf(y, y, z * z)));
    }
    if (i < N_PRE) {
        float x = pre[i], y = pre[N_PRE + i], z = pre[2 * N_PRE + i];
        pre4[i] = make_float4(-2.f * x, -2.f * y, -2.f * z,
                              fmaf(x, x, fmaf(y, y, z * z)));
    }
}

// ---------- Kernel A: cur2pre argmin (R1 structure, ~10us measured) ----
// Wave owns 2 cur queries; lanes scan pre candidates from the LDS tile.
// Branchless running min; strict < + ascending per-lane idx stream ->
// lowest index on ties; cross-lane packed u64 butterfly min.
#define TILE_A 2048

__global__ __launch_bounds__(1024) void cur2pre_kernel(
        const float4* __restrict__ pre4, const float4* __restrict__ cur4,
        unsigned* __restrict__ c2p) {
    __shared__ float4 sp[TILE_A];
    const int tid  = threadIdx.x;
    const int lane = tid & 63;
    const int w    = tid >> 6;
    const int j0   = blockIdx.x * 32 + w * 2;   // this wave's 2 cur points

    const float4 c0 = cur4[j0 + 0];
    const float4 c1 = cur4[j0 + 1];

    const float INF = __int_as_float(0x7F800000);
    float b0 = INF, b1 = INF;
    int   i0 = 0,   i1 = 0;

    for (int tile = 0; tile < N_PRE; tile += TILE_A) {
        __syncthreads();
        for (int k = tid; k < TILE_A; k += 1024) sp[k] = pre4[tile + k];
        __syncthreads();

#pragma unroll 8
        for (int s = 0; s < TILE_A; s += 64) {
            float4 q = sp[s + lane];
            int idx = tile + s + lane;
            float d; bool c;
            d = fmaf(q.x, c0.x, fmaf(q.y, c0.y, fmaf(q.z, c0.z, q.w)));
            c = d < b0; b0 = c ? d : b0; i0 = c ? idx : i0;
            d = fmaf(q.x, c1.x, fmaf(q.y, c1.y, fmaf(q.z, c1.z, q.w)));
            c = d < b1; b1 = c ? d : b1; i1 = c ? idx : i1;
        }
    }

    unsigned long long v0 =
        (((unsigned long long)key_of_bits(__float_as_uint(b0))) << 32) | (unsigned)i0;
    unsigned long long v1 =
        (((unsigned long long)key_of_bits(__float_as_uint(b1))) << 32) | (unsigned)i1;
#pragma unroll
    for (int off = 32; off > 0; off >>= 1) {
        unsigned long long o;
        o = __shfl_xor(v0, off); v0 = (o < v0) ? o : v0;
        o = __shfl_xor(v1, off); v1 = (o < v1) ? o : v1;
    }
    unsigned r = (unsigned)v0;
    r = (lane == 1) ? (unsigned)v1 : r;
    if (lane < 2) c2p[j0 + lane] = r;
}

// ---------- Kernel B: per-pre top-8 + masked mean (cur-split x2) -------
// Block = 8 pres. Waves 0-3: pres (2 each), candidates [0, 8192).
// Waves 4-7: SAME pres, candidates [8192, 16384). Two 16KB LDS tiles.
// Pop event path proven R4 (DPP row_shr:1 + readlane, no LDS-pipe ops).
// Tail: partial lists -> LDS -> 16-elem bitonic merge (packed u64).
#define TILE_B 1024   // per-half tile (float4); 2 tiles = 32KB LDS

__device__ __forceinline__ void pop_top8(float d, float& t8, unsigned& ld,
                                         unsigned& li, int jbase) {
    unsigned long long m = __ballot(d < t8);
    while (m) {
        int src = __ffsll(m) - 1;
        unsigned fdb = (unsigned)__builtin_amdgcn_readlane(__float_as_int(d), src);
        unsigned kd = key_of_bits(fdb);            // uniform (SALU)
        unsigned kj = (unsigned)(jbase + src);     // uniform (SALU)
        // shift-up within 16-lane row; lane 0 receives old=0 (kd<0u never
        // true -> lane 0 never takes the shifted value)
        unsigned ud = (unsigned)__builtin_amdgcn_update_dpp(
            0, (int)ld, 0x111, 0xF, 0xF, false);
        unsigned uj = (unsigned)__builtin_amdgcn_update_dpp(
            0, (int)li, 0x111, 0xF, 0xF, false);
        bool hi = kd < ud;   // belongs below slot-1 -> take shifted value
        bool lo = kd < ld;   // belongs here -> take new
        ld = hi ? ud : (lo ? kd : ld);
        li = hi ? uj : (lo ? kj : li);
        unsigned k7 = (unsigned)__builtin_amdgcn_readlane((int)ld, 7);
        t8 = float_of_key(k7);
        m = (m & (m - 1)) & __ballot(d < t8);
    }
}

__global__ __launch_bounds__(512) void knn_finalize_kernel(
        const float4* __restrict__ pre4, const float4* __restrict__ cur4,
        const float* __restrict__ ups,
        const unsigned* __restrict__ c2p,
        float* __restrict__ out) {
    __shared__ float4 sc[2 * TILE_B];          // [half][TILE_B]
    unsigned long long* mb = (unsigned long long*)sc;  // reused for merge

    const int tid  = threadIdx.x;
    const int lane = tid & 63;
    const int w    = tid >> 6;
    const int half = w >> 2;                   // 0 or 1
    const int wl   = w & 3;                    // wave within half-group
    const int ia   = blockIdx.x * 8 + wl * 2;  // this wave's 2 pres
    const int ib   = ia + 1;
    const int hbase = half * (N_CUR / 2);      // candidate offset of my half

    const float4 p0 = pre4[ia];   // (-2p, |p|^2), wave-uniform
    const float4 p1 = pre4[ib];

    const float INF = __int_as_float(0x7F800000);
    unsigned ld0 = MAPPED_INF, li0 = 0, ld1 = MAPPED_INF, li1 = 0;
    float t80 = INF, t81 = INF;

    for (int tile = 0; tile < N_CUR / 2; tile += TILE_B) {
        __syncthreads();
        // stage both halves' tiles: k<1024 -> half0, k>=1024 -> half1
        for (int k = tid; k < 2 * TILE_B; k += 512) {
            int hh = k >> 10;
            int kk = k & (TILE_B - 1);
            sc[k] = cur4[hh * (N_CUR / 2) + tile + kk];
        }
        __syncthreads();

#pragma unroll 4
        for (int s = 0; s < TILE_B; s += 64) {
            float4 c = sc[half * TILE_B + s + lane];
            float d0 = fmaf(p0.x, c.x, fmaf(p0.y, c.y, fmaf(p0.z, c.z, c.w)));
            float d1 = fmaf(p1.x, c.x, fmaf(p1.y, c.y, fmaf(p1.z, c.z, c.w)));
            const int jbase = hbase + tile + s;
            pop_top8(d0, t80, ld0, li0, jbase);
            pop_top8(d1, t81, ld1, li1, jbase);
        }
    }

    // ---- write partial lists to LDS: mb[pre_local(0..7)][half][slot] ----
    __syncthreads();
    if (lane < 8) {
        mb[((wl * 2 + 0) * 2 + half) * 8 + lane] =
            (((unsigned long long)ld0) << 32) | li0;
        mb[((wl * 2 + 1) * 2 + half) * 8 + lane] =
            (((unsigned long long)ld1) << 32) | li1;
    }
    __syncthreads();

    // ---- merge + finalize: threads 0..127 = 8 pres x 16 lanes ----------
    if (tid < 128) {
        const int g  = tid >> 4;        // pre_local 0..7
        const int t  = tid & 15;        // position in 16-elem sequence
        const int pg = blockIdx.x * 8 + g;

        // ascending half-0 list then REVERSED half-1 list -> bitonic
        unsigned long long v = (t < 8) ? mb[(g * 2 + 0) * 8 + t]
                                       : mb[(g * 2 + 1) * 8 + (15 - t)];
#pragma unroll
        for (int off = 8; off > 0; off >>= 1) {
            unsigned long long o = __shfl_xor(v, off);
            bool up = (t & off) != 0;
            v = up ? ((o > v) ? o : v) : ((o < v) ? o : v);
        }
        // lanes t=0..7 now hold the global top-8 (ascending key,idx)

        float acc = 0.f;
        if (t < 8) {
            unsigned j = (unsigned)v;
            float4 cc = cur4[j];
            float4 pp = pre4[pg];
            float px = -0.5f * pp.x, py = -0.5f * pp.y, pz = -0.5f * pp.z;
            float dx = cc.x - px, dy = cc.y - py, dz = cc.z - pz;
            float dsq = fmaf(dx, dx, fmaf(dy, dy, dz * dz));
            acc = (c2p[j] == (unsigned)pg) ? sqrtf(dsq) : 0.f;
        }
        acc += __shfl_xor(acc, 1);
        acc += __shfl_xor(acc, 2);
        acc += __shfl_xor(acc, 4);
        if (t == 0) out[pg] = acc / ups[pg];
    }
}

// ---------- launch ----------
extern "C" void kernel_launch(void* const* d_in, const int* in_sizes, int n_in,
                              void* d_out, int out_size, void* d_ws, size_t ws_size,
                              hipStream_t stream) {
    const float* pre = (const float*)d_in[0];   // (1,3,8192)
    const float* cur = (const float*)d_in[1];   // (1,3,16384)
    const float* ups = (const float*)d_in[2];   // (1,8192)
    float* out = (float*)d_out;                 // (1,8192)

    char* ws = (char*)d_ws;
    unsigned* c2p = (unsigned*)ws;                    //  64 KB
    float4*   pre4 = (float4*)(ws + 65536);           // 128 KB
    float4*   cur4 = (float4*)(ws + 65536 + 131072);  // 256 KB

    prep_kernel<<<N_CUR / 256, 256, 0, stream>>>(pre, cur, pre4, cur4);

    // A: 512 blocks x 16 waves, 2 cur/wave (R1 config, ~10us)
    cur2pre_kernel<<<N_CUR / 32, 1024, 0, stream>>>(pre4, cur4, c2p);

    // B: 1024 blocks x 8 waves (4 per cur-half), 2 pres/wave, 8 pres/block
    knn_finalize_kernel<<<N_PRE / 8, 512, 0, stream>>>(pre4, cur4, ups, c2p, out);
}